// Round 4
// baseline (2526.946 us; speedup 1.0000x reference)
//
#include <hip/hip_runtime.h>
#include <math.h>

// Problem constants
#define B_  256
#define T_  32
#define S_  128
#define I_  256
#define H_  1024
#define O_  256
#define G4  4096   // 4*H
#define K2  2048   // 2*H

typedef __attribute__((ext_vector_type(8))) short bf16x8;
typedef __attribute__((ext_vector_type(4))) float f32x4;

#define MFMA16(a, b, c) __builtin_amdgcn_mfma_f32_16x16x32_bf16(a, b, c, 0, 0, 0)

__device__ __forceinline__ unsigned short f2bf(float f) {
    unsigned int u = __float_as_uint(f);
    u = (u + 0x7FFFu + ((u >> 16) & 1u)) >> 16;
    return (unsigned short)u;
}
__device__ __forceinline__ unsigned int pack2(float a, float b) {
    return (unsigned int)f2bf(a) | ((unsigned int)f2bf(b) << 16);
}
__device__ __forceinline__ uint4 cvt8(const float* p) {
    float4 f0 = *(const float4*)p;
    float4 f1 = *(const float4*)(p + 4);
    uint4 v;
    v.x = pack2(f0.x, f0.y); v.y = pack2(f0.z, f0.w);
    v.z = pack2(f1.x, f1.y); v.w = pack2(f1.z, f1.w);
    return v;
}
__device__ __forceinline__ float sigm(float x) { return 1.0f / (1.0f + __expf(-x)); }

// ---------------------------------------------------------------------------
// prep: vectorized (8 elem/thread) bf16 convert + gate-reorder.
// Gate reorder: orig row r -> n = 4*(r%H) + (r/H).
// ---------------------------------------------------------------------------
__global__ void prep_kernel(
    const float* __restrict__ x, const float* __restrict__ enc,
    const float* __restrict__ Wih, const float* __restrict__ Whh,
    const float* __restrict__ bih, const float* __restrict__ bhh,
    const float* __restrict__ Wfc,
    unsigned short* __restrict__ WihR, unsigned short* __restrict__ WhhR,
    unsigned short* __restrict__ WfcR, float* __restrict__ biasR,
    unsigned short* __restrict__ xs, unsigned short* __restrict__ encB,
    unsigned short* __restrict__ h0)
{
    const long U_ENC = ((long)B_ * S_ * H_) >> 3;  // 4,194,304
    const long U_WHH = ((long)G4 * H_) >> 3;       //   524,288
    const long U_WIH = ((long)G4 * I_) >> 3;       //   131,072
    const long U_WFC = ((long)O_ * K2) >> 3;       //    65,536
    const long U_X   = ((long)B_ * T_ * I_) >> 3;  //   262,144
    const long U_H0  = ((long)B_ * H_) >> 3;       //    32,768
    const long U_B   = G4 >> 3;                    //       512
    const long total = U_ENC + U_WHH + U_WIH + U_WFC + U_X + U_H0 + U_B;
    for (long i = (long)blockIdx.x * blockDim.x + threadIdx.x; i < total;
         i += (long)gridDim.x * blockDim.x) {
        long j = i;
        if (j < U_ENC) {
            long e = j << 3;
            *(uint4*)(encB + e) = cvt8(enc + e);
            continue;
        }
        j -= U_ENC;
        if (j < U_WHH) {
            long e = j << 3;
            int r = (int)(e >> 10), k = (int)(e & 1023);
            int n = ((r & 1023) << 2) | (r >> 10);
            *(uint4*)(WhhR + (long)n * H_ + k) = cvt8(Whh + e);
            continue;
        }
        j -= U_WHH;
        if (j < U_WIH) {
            long e = j << 3;
            int r = (int)(e >> 8), k = (int)(e & 255);
            int n = ((r & 1023) << 2) | (r >> 10);
            *(uint4*)(WihR + (long)n * I_ + k) = cvt8(Wih + e);
            continue;
        }
        j -= U_WIH;
        if (j < U_WFC) {
            long e = j << 3;
            *(uint4*)(WfcR + e) = cvt8(Wfc + e);
            continue;
        }
        j -= U_WFC;
        if (j < U_X) {
            long e = j << 3;
            int tt = (int)((e >> 8) & 31);
            if (tt == 0) {
                uint4 zz = {0u, 0u, 0u, 0u};
                *(uint4*)(xs + e) = zz;
            } else {
                *(uint4*)(xs + e) = cvt8(x + e);
            }
            continue;
        }
        j -= U_X;
        if (j < U_H0) {
            uint4 zz = {0u, 0u, 0u, 0u};
            *(uint4*)(h0 + (j << 3)) = zz;
            continue;
        }
        j -= U_H0;
        {
            long e = j << 3;
#pragma unroll
            for (int q = 0; q < 8; q++) {
                int r = (int)e + q;
                int n = ((r & 1023) << 2) | (r >> 10);
                biasR[n] = bih[r] + bhh[r];
            }
        }
    }
}

// ---------------------------------------------------------------------------
// rec: persistent LSTM recurrence, PLAIN launch (grid=256 blocks = #CUs;
// 64 KB LDS + 4 waves => capacity >= 2 blocks/CU, so all blocks co-resident
// by construction; hand-rolled agent-scope barrier).
// Block owns 64m x 64n gate tile; wave w holds K-slice [320w,320w+320) of the
// B-tile (40 bf16x8 = 160 VGPRs) for ALL 32 steps -- weights read once.
// Per step: 40 direct A-loads + 160 MFMAs/wave, k-partials reduced via 64 KB
// LDS, fused LSTM cell (c in registers across steps), h double-buffered in
// global, one grid barrier per step.
// ---------------------------------------------------------------------------
__global__ __launch_bounds__(256, 1) void rec_kernel(
    const unsigned short* __restrict__ xs,   // [B][T][I] bf16
    const unsigned short* __restrict__ WihR, // [4H][I]
    const unsigned short* __restrict__ WhhR, // [4H][H]
    const float* __restrict__ biasR,         // [4H]
    unsigned short* __restrict__ h0,         // [B][H] (zeroed)
    unsigned short* __restrict__ h1,         // [B][H]
    unsigned short* __restrict__ hall,       // [B][T][H]
    unsigned int* __restrict__ bar)          // grid barrier counter (zeroed)
{
    __shared__ float P[4][64][64];  // 64 KB: per-wave k-partials

    const int tid = threadIdx.x;
    const int lane = tid & 63, wave = tid >> 6;
    const int quad = lane >> 4, l16 = lane & 15;
    const int bx = blockIdx.x;
    const int n0 = (bx & 63) * 64;   // gate-col tile (16 units)
    const int m0 = (bx >> 6) * 64;   // batch tile
    const int wk0 = wave * 320;      // this wave's K-slice

    // --- B fragments resident in VGPRs: [ni][kk] ---
    bf16x8 bfrag[4][10];
#pragma unroll
    for (int ni = 0; ni < 4; ni++) {
        const long nr = n0 + ni * 16 + l16;
#pragma unroll
        for (int kk = 0; kk < 10; kk++) {
            int kg = wk0 + kk * 32 + quad * 8;
            bfrag[ni][kk] = (kg < I_)
                ? *(const bf16x8*)(WihR + nr * I_ + kg)
                : *(const bf16x8*)(WhhR + nr * H_ + (kg - I_));
        }
    }

    // --- epilogue assignment: thread -> (row, 4 units) ---
    const int erow = tid >> 2;       // 0..63
    const int eu4 = (tid & 3) * 4;   // unit group base within tile
    f32x4 bias4[4];
#pragma unroll
    for (int uu = 0; uu < 4; uu++)
        bias4[uu] = *(const f32x4*)(biasR + n0 + (eu4 + uu) * 4);
    float creg[4] = {0.f, 0.f, 0.f, 0.f};

    const long hwoff = (long)(m0 + erow) * H_ + (n0 >> 2) + eu4;

    for (int t = 0; t < T_; t++) {
        const unsigned short* hc = (t & 1) ? h1 : h0;
        unsigned short* hn = (t & 1) ? h0 : h1;

        f32x4 acc[4][4];
        const f32x4 z = {0.f, 0.f, 0.f, 0.f};
#pragma unroll
        for (int mi = 0; mi < 4; mi++)
#pragma unroll
            for (int ni = 0; ni < 4; ni++) acc[mi][ni] = z;

#pragma unroll
        for (int kk = 0; kk < 10; kk++) {
            int kg = wk0 + kk * 32 + quad * 8;
            bf16x8 a[4];
            if (kg < I_) {  // wave-uniform branch (only wave 0, kk<8)
#pragma unroll
                for (int mi = 0; mi < 4; mi++)
                    a[mi] = *(const bf16x8*)(xs +
                        ((long)(m0 + mi * 16 + l16) * T_ + t) * I_ + kg);
            } else {
#pragma unroll
                for (int mi = 0; mi < 4; mi++)
                    a[mi] = *(const bf16x8*)(hc +
                        (long)(m0 + mi * 16 + l16) * H_ + (kg - I_));
            }
#pragma unroll
            for (int ni = 0; ni < 4; ni++)
#pragma unroll
                for (int mi = 0; mi < 4; mi++)
                    acc[mi][ni] = MFMA16(a[mi], bfrag[ni][kk], acc[mi][ni]);
        }

        // k-partials -> LDS (C layout: row = quad*4+r, col = l16)
#pragma unroll
        for (int mi = 0; mi < 4; mi++)
#pragma unroll
            for (int ni = 0; ni < 4; ni++)
#pragma unroll
                for (int r = 0; r < 4; r++)
                    P[wave][mi * 16 + quad * 4 + r][ni * 16 + l16] = acc[mi][ni][r];
        __syncthreads();

        // reduce 4 waves + fused cell for 4 cells (erow, eu4+uu)
        unsigned int hv[2];
        {
            unsigned short hbuf[4];
#pragma unroll
            for (int uu = 0; uu < 4; uu++) {
                f32x4 g = bias4[uu];
#pragma unroll
                for (int w = 0; w < 4; w++) {
                    f32x4 pv = *(const f32x4*)&P[w][erow][(eu4 + uu) * 4];
                    g[0] += pv[0]; g[1] += pv[1]; g[2] += pv[2]; g[3] += pv[3];
                }
                float ii = sigm(g[0]), ff = sigm(g[1]);
                float gg = tanhf(g[2]), oo = sigm(g[3]);
                float cn = ff * creg[uu] + ii * gg;
                creg[uu] = cn;
                hbuf[uu] = f2bf(oo * tanhf(cn));
            }
            hv[0] = (unsigned int)hbuf[0] | ((unsigned int)hbuf[1] << 16);
            hv[1] = (unsigned int)hbuf[2] | ((unsigned int)hbuf[3] << 16);
        }
        *(uint2*)(hn + hwoff) = *(uint2*)hv;
        *(uint2*)(hall + ((long)(m0 + erow) * T_ + t) * H_ + (n0 >> 2) + eu4) =
            *(uint2*)hv;

        // --- device-scope grid barrier (all 256 blocks resident) ---
        __threadfence();
        __syncthreads();
        if (tid == 0) {
            __hip_atomic_fetch_add(bar, 1u, __ATOMIC_ACQ_REL,
                                   __HIP_MEMORY_SCOPE_AGENT);
            const unsigned int tgt = 256u * (unsigned int)(t + 1);
            while (__hip_atomic_load(bar, __ATOMIC_ACQUIRE,
                                     __HIP_MEMORY_SCOPE_AGENT) < tgt)
                __builtin_amdgcn_s_sleep(2);
        }
        __syncthreads();
        __threadfence();
    }
}

// ---------------------------------------------------------------------------
// scores: per-b S = hall[b](32x1024) @ encB[b](128x1024)^T, fused softmax.
// ---------------------------------------------------------------------------
__global__ __launch_bounds__(256) void scores_kernel(
    const unsigned short* __restrict__ hall, // [B][T][H]
    const unsigned short* __restrict__ encB, // [B][S][H]
    float* __restrict__ probs,               // [B][T][S]
    unsigned short* __restrict__ PB)         // [B][T][S] bf16
{
    __shared__ float Sc[32 * 132];

    const int tid = threadIdx.x;
    const int lane = tid & 63, wave = tid >> 6;
    const int quad = lane >> 4, l16 = lane & 15;
    const int b = blockIdx.x;
    const int nw = wave;

    const unsigned short* pa0 = hall + ((long)b * T_ + l16) * H_ + quad * 8;
    const unsigned short* pa1 = hall + ((long)b * T_ + 16 + l16) * H_ + quad * 8;
    const unsigned short* pb0 = encB + ((long)b * S_ + nw * 32 + l16) * H_ + quad * 8;
    const unsigned short* pb1 = pb0 + 16 * H_;

    const f32x4 z = {0.f, 0.f, 0.f, 0.f};
    f32x4 acc00 = z, acc01 = z, acc10 = z, acc11 = z;

#pragma unroll 4
    for (int k0 = 0; k0 < H_; k0 += 32) {
        bf16x8 a0 = *(const bf16x8*)(pa0 + k0);
        bf16x8 a1 = *(const bf16x8*)(pa1 + k0);
        bf16x8 b0 = *(const bf16x8*)(pb0 + k0);
        bf16x8 b1 = *(const bf16x8*)(pb1 + k0);
        acc00 = MFMA16(a0, b0, acc00);
        acc01 = MFMA16(a0, b1, acc01);
        acc10 = MFMA16(a1, b0, acc10);
        acc11 = MFMA16(a1, b1, acc11);
    }
#pragma unroll
    for (int r = 0; r < 4; r++) {
        int row0 = quad * 4 + r;
        int col0 = nw * 32 + l16;
        Sc[row0 * 132 + col0]            = acc00[r];
        Sc[row0 * 132 + col0 + 16]       = acc01[r];
        Sc[(row0 + 16) * 132 + col0]      = acc10[r];
        Sc[(row0 + 16) * 132 + col0 + 16] = acc11[r];
    }
    __syncthreads();
    for (int r = 0; r < 8; r++) {
        int row = wave * 8 + r;
        float v0 = Sc[row * 132 + lane];
        float v1 = Sc[row * 132 + 64 + lane];
        float mx = fmaxf(v0, v1);
#pragma unroll
        for (int off = 32; off > 0; off >>= 1) mx = fmaxf(mx, __shfl_xor(mx, off));
        float e0 = __expf(v0 - mx), e1 = __expf(v1 - mx);
        float s = e0 + e1;
#pragma unroll
        for (int off = 32; off > 0; off >>= 1) s += __shfl_xor(s, off);
        float inv = 1.0f / s;
        float p0 = e0 * inv, p1 = e1 * inv;
        long o = ((long)b * T_ + row) * S_;
        probs[o + lane] = p0;
        probs[o + 64 + lane] = p1;
        PB[o + lane] = f2bf(p0);
        PB[o + 64 + lane] = f2bf(p1);
    }
}

// ---------------------------------------------------------------------------
// ctx: C[b] = P[b](32x128) @ encB[b](128x1024) -> CTX bf16. grid(B, 4).
// ---------------------------------------------------------------------------
__global__ __launch_bounds__(256) void ctx_kernel(
    const unsigned short* __restrict__ encB, // [B][S][H]
    const unsigned short* __restrict__ PB,   // [B][T][S]
    unsigned short* __restrict__ ctxo)       // [B*T][H] bf16
{
    __shared__ unsigned short Es[S_ * 256];  // 64 KB

    const int tid = threadIdx.x;
    const int lane = tid & 63, wave = tid >> 6;
    const int quad = lane >> 4, l16 = lane & 15;
    const int b = blockIdx.x;
    const int h0 = blockIdx.y * 256;

    for (int i = tid; i < S_ * 32; i += 256) {
        int s = i >> 5, hc = (i & 31) * 8;
        *(uint4*)(Es + s * 256 + hc) =
            *(const uint4*)(encB + ((long)b * S_ + s) * H_ + h0 + hc);
    }
    bf16x8 a[2][4];
#pragma unroll
    for (int i = 0; i < 2; i++)
#pragma unroll
        for (int ks = 0; ks < 4; ks++)
            a[i][ks] = *(const bf16x8*)(PB + ((long)b * T_ + i * 16 + l16) * S_ +
                                        ks * 32 + quad * 8);
    __syncthreads();

    f32x4 acc[2][4];
    const f32x4 z = {0.f, 0.f, 0.f, 0.f};
#pragma unroll
    for (int i = 0; i < 2; i++)
#pragma unroll
        for (int j = 0; j < 4; j++) acc[i][j] = z;

    const int cw = wave * 64;
#pragma unroll
    for (int ks = 0; ks < 4; ks++) {
        const int kb = ks * 32 + quad * 8;
#pragma unroll
        for (int j = 0; j < 4; j++) {
            const int col = cw + j * 16 + l16;
            bf16x8 bb;
#pragma unroll
            for (int e = 0; e < 8; e++) bb[e] = (short)Es[(kb + e) * 256 + col];
            acc[0][j] = MFMA16(a[0][ks], bb, acc[0][j]);
            acc[1][j] = MFMA16(a[1][ks], bb, acc[1][j]);
        }
    }
#pragma unroll
    for (int i = 0; i < 2; i++)
#pragma unroll
        for (int j = 0; j < 4; j++)
#pragma unroll
            for (int r = 0; r < 4; r++) {
                int row = i * 16 + quad * 4 + r;
                int col = h0 + cw + j * 16 + l16;
                ctxo[((long)b * T_ + row) * H_ + col] = f2bf(acc[i][j][r]);
            }
}

// ---------------------------------------------------------------------------
// fc: out = [ctx | h](8192x2048) @ WfcR^T (256x2048) + bfc. grid(2,128).
// ---------------------------------------------------------------------------
__global__ __launch_bounds__(256) void fc_kernel(
    const unsigned short* __restrict__ ctxo, // [B*T][H]
    const unsigned short* __restrict__ hall, // [B*T][H]
    const unsigned short* __restrict__ WfcR,
    const float* __restrict__ bfc,
    float* __restrict__ out)
{
    __shared__ __align__(16) unsigned short As[64 * 40];
    __shared__ __align__(16) unsigned short Bs[128 * 40];

    const int tid = threadIdx.x;
    const int lane = tid & 63, wave = tid >> 6;
    const int wm = wave >> 1, wn = wave & 1;
    const int quad = lane >> 4, l16 = lane & 15;
    const int n0 = blockIdx.x * 128, m0 = blockIdx.y * 64;

    const int arow = tid >> 2, akc = (tid & 3) * 8;
    const int brow = tid >> 1, bkc = (tid & 1) * 16;

    f32x4 acc[2][4];
    const f32x4 z = {0.f, 0.f, 0.f, 0.f};
#pragma unroll
    for (int i = 0; i < 2; i++)
#pragma unroll
        for (int j = 0; j < 4; j++) acc[i][j] = z;

    for (int k0 = 0; k0 < K2; k0 += 32) {
        const unsigned short* asrc = (k0 < H_)
            ? ctxo + (long)(m0 + arow) * H_ + k0 + akc
            : hall + (long)(m0 + arow) * H_ + (k0 - H_) + akc;
        *(uint4*)(As + arow * 40 + akc) = *(const uint4*)asrc;
        const unsigned short* src = WfcR + (long)(n0 + brow) * K2 + k0 + bkc;
        *(uint4*)(Bs + brow * 40 + bkc)     = *(const uint4*)src;
        *(uint4*)(Bs + brow * 40 + bkc + 8) = *(const uint4*)(src + 8);
        __syncthreads();
        bf16x8 a0 = *(const bf16x8*)(As + (wm * 32 + l16) * 40 + quad * 8);
        bf16x8 a1 = *(const bf16x8*)(As + (wm * 32 + 16 + l16) * 40 + quad * 8);
#pragma unroll
        for (int j = 0; j < 4; j++) {
            bf16x8 bb = *(const bf16x8*)(Bs + (wn * 64 + j * 16 + l16) * 40 + quad * 8);
            acc[0][j] = MFMA16(a0, bb, acc[0][j]);
            acc[1][j] = MFMA16(a1, bb, acc[1][j]);
        }
        __syncthreads();
    }
#pragma unroll
    for (int i = 0; i < 2; i++)
#pragma unroll
        for (int j = 0; j < 4; j++)
#pragma unroll
            for (int r = 0; r < 4; r++) {
                int row = m0 + wm * 32 + i * 16 + quad * 4 + r;
                int col = n0 + wn * 64 + j * 16 + l16;
                out[(long)row * O_ + col] = acc[i][j][r] + bfc[col];
            }
}

// ---------------------------------------------------------------------------
extern "C" void kernel_launch(void* const* d_in, const int* in_sizes, int n_in,
                              void* d_out, int out_size, void* d_ws, size_t ws_size,
                              hipStream_t stream) {
    const float* x   = (const float*)d_in[0];
    const float* enc = (const float*)d_in[1];
    const float* Wih = (const float*)d_in[2];
    const float* Whh = (const float*)d_in[3];
    const float* bih = (const float*)d_in[4];
    const float* bhh = (const float*)d_in[5];
    const float* Wfc = (const float*)d_in[6];
    const float* bfc = (const float*)d_in[7];
    float* out = (float*)d_out;

    char* ws = (char*)d_ws;
    // workspace layout (bytes); total ~119.6 MB
    unsigned short* WIHR = (unsigned short*)(ws + 0);           //  2,097,152
    unsigned short* WHHR = (unsigned short*)(ws + 2097152);     //  8,388,608
    unsigned short* WFCR = (unsigned short*)(ws + 10485760);    //  1,048,576
    float*          BIAS = (float*)         (ws + 11534336);    //     16,384
    unsigned short* XS   = (unsigned short*)(ws + 11550720);    //  4,194,304
    unsigned short* H0   = (unsigned short*)(ws + 15745024);    //    524,288
    unsigned short* H1   = (unsigned short*)(ws + 16269312);    //    524,288
    unsigned short* HALL = (unsigned short*)(ws + 16793600);    // 16,777,216
    unsigned short* ENCB = (unsigned short*)(ws + 33570816);    // 67,108,864
    unsigned short* PB   = (unsigned short*)(ws + 100679680);   //  2,097,152
    unsigned short* CTX  = (unsigned short*)(ws + 102776832);   // 16,777,216
    unsigned int*   BAR  = (unsigned int*)  (ws + 119554048);   //        256

    hipMemsetAsync(BAR, 0, 256, stream);

    prep_kernel<<<4096, 256, 0, stream>>>(x, enc, Wih, Whh, bih, bhh, Wfc,
                                          WIHR, WHHR, WFCR, BIAS, XS, ENCB, H0);

    rec_kernel<<<256, 256, 0, stream>>>(XS, WIHR, WHHR, BIAS, H0, H1, HALL, BAR);

    scores_kernel<<<B_, 256, 0, stream>>>(HALL, ENCB,
                                          out + (long)B_ * T_ * O_, PB);
    ctx_kernel<<<dim3(B_, 4), 256, 0, stream>>>(ENCB, PB, CTX);
    fc_kernel<<<dim3(2, 128), 256, 0, stream>>>(CTX, HALL, WFCR, bfc, out);
}

// Round 5
// 1342.332 us; speedup vs baseline: 1.8825x; 1.8825x over previous
//
#include <hip/hip_runtime.h>
#include <math.h>

// Problem constants
#define B_  256
#define T_  32
#define S_  128
#define I_  256
#define H_  1024
#define O_  256
#define G4  4096   // 4*H
#define K2  2048   // 2*H

typedef __attribute__((ext_vector_type(8))) short bf16x8;
typedef __attribute__((ext_vector_type(4))) float f32x4;

#define MFMA16(a, b, c) __builtin_amdgcn_mfma_f32_16x16x32_bf16(a, b, c, 0, 0, 0)

__device__ __forceinline__ unsigned short f2bf(float f) {
    unsigned int u = __float_as_uint(f);
    u = (u + 0x7FFFu + ((u >> 16) & 1u)) >> 16;
    return (unsigned short)u;
}
__device__ __forceinline__ unsigned int pack2(float a, float b) {
    return (unsigned int)f2bf(a) | ((unsigned int)f2bf(b) << 16);
}
__device__ __forceinline__ uint4 cvt8(const float* p) {
    float4 f0 = *(const float4*)p;
    float4 f1 = *(const float4*)(p + 4);
    uint4 v;
    v.x = pack2(f0.x, f0.y); v.y = pack2(f0.z, f0.w);
    v.z = pack2(f1.x, f1.y); v.w = pack2(f1.z, f1.w);
    return v;
}
__device__ __forceinline__ float sigm(float x) { return 1.0f / (1.0f + __expf(-x)); }

// ---------------------------------------------------------------------------
// prep: vectorized (8 elem/thread) bf16 convert + gate-reorder.
// Gate reorder: orig row r -> n = 4*(r%H) + (r/H).
// ---------------------------------------------------------------------------
__global__ void prep_kernel(
    const float* __restrict__ x, const float* __restrict__ enc,
    const float* __restrict__ Wih, const float* __restrict__ Whh,
    const float* __restrict__ bih, const float* __restrict__ bhh,
    const float* __restrict__ Wfc,
    unsigned short* __restrict__ WihR, unsigned short* __restrict__ WhhR,
    unsigned short* __restrict__ WfcR, float* __restrict__ biasR,
    unsigned short* __restrict__ xs, unsigned short* __restrict__ encB,
    unsigned short* __restrict__ h0)
{
    const long U_ENC = ((long)B_ * S_ * H_) >> 3;  // 4,194,304
    const long U_WHH = ((long)G4 * H_) >> 3;       //   524,288
    const long U_WIH = ((long)G4 * I_) >> 3;       //   131,072
    const long U_WFC = ((long)O_ * K2) >> 3;       //    65,536
    const long U_X   = ((long)B_ * T_ * I_) >> 3;  //   262,144
    const long U_H0  = ((long)B_ * H_) >> 3;       //    32,768
    const long U_B   = G4 >> 3;                    //       512
    const long total = U_ENC + U_WHH + U_WIH + U_WFC + U_X + U_H0 + U_B;
    for (long i = (long)blockIdx.x * blockDim.x + threadIdx.x; i < total;
         i += (long)gridDim.x * blockDim.x) {
        long j = i;
        if (j < U_ENC) {
            long e = j << 3;
            *(uint4*)(encB + e) = cvt8(enc + e);
            continue;
        }
        j -= U_ENC;
        if (j < U_WHH) {
            long e = j << 3;
            int r = (int)(e >> 10), k = (int)(e & 1023);
            int n = ((r & 1023) << 2) | (r >> 10);
            *(uint4*)(WhhR + (long)n * H_ + k) = cvt8(Whh + e);
            continue;
        }
        j -= U_WHH;
        if (j < U_WIH) {
            long e = j << 3;
            int r = (int)(e >> 8), k = (int)(e & 255);
            int n = ((r & 1023) << 2) | (r >> 10);
            *(uint4*)(WihR + (long)n * I_ + k) = cvt8(Wih + e);
            continue;
        }
        j -= U_WIH;
        if (j < U_WFC) {
            long e = j << 3;
            *(uint4*)(WfcR + e) = cvt8(Wfc + e);
            continue;
        }
        j -= U_WFC;
        if (j < U_X) {
            long e = j << 3;
            int tt = (int)((e >> 8) & 31);
            if (tt == 0) {
                uint4 zz = {0u, 0u, 0u, 0u};
                *(uint4*)(xs + e) = zz;
            } else {
                *(uint4*)(xs + e) = cvt8(x + e);
            }
            continue;
        }
        j -= U_X;
        if (j < U_H0) {
            uint4 zz = {0u, 0u, 0u, 0u};
            *(uint4*)(h0 + (j << 3)) = zz;
            continue;
        }
        j -= U_H0;
        {
            long e = j << 3;
#pragma unroll
            for (int q = 0; q < 8; q++) {
                int r = (int)e + q;
                int n = ((r & 1023) << 2) | (r >> 10);
                biasR[n] = bih[r] + bhh[r];
            }
        }
    }
}

// ---------------------------------------------------------------------------
// rec: persistent LSTM recurrence. 256 blocks (1/CU) x 512 threads (8 waves).
// Wave (wk = w>>2, wn = w&3): n-slice 16 cols (4 units), K interleaved 2-way:
// kg = (2*kk+wk)*32 + quad*8, kk<20 (kk<4 -> xs, else h). B-slice = 20 bf16x8
// = 80 VGPR, resident for all 32 steps. Per step: 80 A-loads + 80 MFMAs/wave,
// 2-plane LDS reduce (padded, conflict-light), fused cell in waves 0-3 (c in
// registers), h double-buffered in global.
// Grid barrier: 4 per-m-group counters (64 blocks each), relaxed spin +
// one-shot agent release/acquire fences (NO per-poll invalidate).
// ---------------------------------------------------------------------------
__global__ __launch_bounds__(512, 2) void rec_kernel(
    const unsigned short* __restrict__ xs,   // [B][T][I] bf16
    const unsigned short* __restrict__ WihR, // [4H][I]
    const unsigned short* __restrict__ WhhR, // [4H][H]
    const float* __restrict__ biasR,         // [4H]
    unsigned short* __restrict__ h0,         // [B][H] (zeroed)
    unsigned short* __restrict__ h1,         // [B][H]
    unsigned short* __restrict__ hall,       // [B][T][H]
    unsigned int* __restrict__ bar)          // 4 counters, 64B apart (zeroed)
{
    __shared__ float P[2][4][64][20];  // 40960 B

    const int tid = threadIdx.x;
    const int lane = tid & 63, w = tid >> 6;
    const int wk = w >> 2, wn = w & 3;
    const int quad = lane >> 4, l16 = lane & 15;
    const int bx = blockIdx.x;
    const int n0 = (bx & 63) * 64;   // gate-col tile
    const int m0 = (bx >> 6) * 64;   // batch tile
    const int grp = bx >> 6;         // barrier group (same m0)

    // --- B fragments resident in VGPRs ---
    bf16x8 bfrag[20];
    {
        const long nr = n0 + wn * 16 + l16;
#pragma unroll
        for (int kk = 0; kk < 20; kk++) {
            const int kg = (2 * kk + wk) * 32 + quad * 8;
            bfrag[kk] = (kk < 4)
                ? *(const bf16x8*)(WihR + nr * I_ + kg)
                : *(const bf16x8*)(WhhR + nr * H_ + (kg - I_));
        }
    }

    // cell-phase constants (waves 0..3 only; wn == w there)
    f32x4 bias4[4];
#pragma unroll
    for (int u = 0; u < 4; u++)
        bias4[u] = *(const f32x4*)(biasR + n0 + wn * 16 + u * 4);
    float creg[4] = {0.f, 0.f, 0.f, 0.f};
    const int j0 = (n0 >> 2) + wn * 4;   // h column base for cell phase

    for (int t = 0; t < T_; t++) {
        const unsigned short* hc = (t & 1) ? h1 : h0;
        unsigned short* hn = (t & 1) ? h0 : h1;

        f32x4 acc[4];
        const f32x4 z = {0.f, 0.f, 0.f, 0.f};
#pragma unroll
        for (int mi = 0; mi < 4; mi++) acc[mi] = z;

        const unsigned short* pa[4];
#pragma unroll
        for (int mi = 0; mi < 4; mi++) {
            const long row = m0 + mi * 16 + l16;
            pa[mi] = hc + row * H_;  // h base; xs handled separately below
        }

#pragma unroll
        for (int kk = 0; kk < 20; kk++) {
            const int kg = (2 * kk + wk) * 32 + quad * 8;
            bf16x8 a[4];
            if (kk < 4) {
#pragma unroll
                for (int mi = 0; mi < 4; mi++)
                    a[mi] = *(const bf16x8*)(xs +
                        ((long)(m0 + mi * 16 + l16) * T_ + t) * I_ + kg);
            } else {
#pragma unroll
                for (int mi = 0; mi < 4; mi++)
                    a[mi] = *(const bf16x8*)(pa[mi] + (kg - I_));
            }
#pragma unroll
            for (int mi = 0; mi < 4; mi++)
                acc[mi] = MFMA16(a[mi], bfrag[kk], acc[mi]);
        }

        // partials -> LDS (C layout: row = mi*16 + quad*4 + r, col = l16)
#pragma unroll
        for (int mi = 0; mi < 4; mi++)
#pragma unroll
            for (int r = 0; r < 4; r++)
                P[wk][wn][mi * 16 + quad * 4 + r][l16] = acc[mi][r];
        __syncthreads();

        // cell phase: waves 0..3, lane = row, 4 units each
        if (w < 4) {
            unsigned short hbuf[4];
#pragma unroll
            for (int u = 0; u < 4; u++) {
                f32x4 p0 = *(const f32x4*)&P[0][wn][lane][u * 4];
                f32x4 p1 = *(const f32x4*)&P[1][wn][lane][u * 4];
                float gi = bias4[u][0] + p0[0] + p1[0];
                float gf = bias4[u][1] + p0[1] + p1[1];
                float gg = bias4[u][2] + p0[2] + p1[2];
                float go = bias4[u][3] + p0[3] + p1[3];
                float ii = sigm(gi), ff = sigm(gf);
                float g3 = tanhf(gg), oo = sigm(go);
                float cn = ff * creg[u] + ii * g3;
                creg[u] = cn;
                hbuf[u] = f2bf(oo * tanhf(cn));
            }
            unsigned int hv[2];
            hv[0] = (unsigned int)hbuf[0] | ((unsigned int)hbuf[1] << 16);
            hv[1] = (unsigned int)hbuf[2] | ((unsigned int)hbuf[3] << 16);
            *(uint2*)(hn + (long)(m0 + lane) * H_ + j0) = *(uint2*)hv;
            *(uint2*)(hall + ((long)(m0 + lane) * T_ + t) * H_ + j0) = *(uint2*)hv;
        }

        // --- grid barrier (per m-group, 64 blocks) ---
        __syncthreads();  // drains all waves' vmem before signaling
        if (tid == 0) {
            __builtin_amdgcn_fence(__ATOMIC_RELEASE, "agent");
            __hip_atomic_fetch_add(&bar[grp * 16], 1u, __ATOMIC_RELAXED,
                                   __HIP_MEMORY_SCOPE_AGENT);
            const unsigned int tgt = 64u * (unsigned int)(t + 1);
            while (__hip_atomic_load(&bar[grp * 16], __ATOMIC_RELAXED,
                                     __HIP_MEMORY_SCOPE_AGENT) < tgt)
                __builtin_amdgcn_s_sleep(1);
            __builtin_amdgcn_fence(__ATOMIC_ACQUIRE, "agent");
        }
        __syncthreads();
    }
}

// ---------------------------------------------------------------------------
// scores: per-b S = hall[b](32x1024) @ encB[b](128x1024)^T, fused softmax.
// ---------------------------------------------------------------------------
__global__ __launch_bounds__(256) void scores_kernel(
    const unsigned short* __restrict__ hall, // [B][T][H]
    const unsigned short* __restrict__ encB, // [B][S][H]
    float* __restrict__ probs,               // [B][T][S]
    unsigned short* __restrict__ PB)         // [B][T][S] bf16
{
    __shared__ float Sc[32 * 132];

    const int tid = threadIdx.x;
    const int lane = tid & 63, wave = tid >> 6;
    const int quad = lane >> 4, l16 = lane & 15;
    const int b = blockIdx.x;
    const int nw = wave;

    const unsigned short* pa0 = hall + ((long)b * T_ + l16) * H_ + quad * 8;
    const unsigned short* pa1 = hall + ((long)b * T_ + 16 + l16) * H_ + quad * 8;
    const unsigned short* pb0 = encB + ((long)b * S_ + nw * 32 + l16) * H_ + quad * 8;
    const unsigned short* pb1 = pb0 + 16 * H_;

    const f32x4 z = {0.f, 0.f, 0.f, 0.f};
    f32x4 acc00 = z, acc01 = z, acc10 = z, acc11 = z;

#pragma unroll 4
    for (int k0 = 0; k0 < H_; k0 += 32) {
        bf16x8 a0 = *(const bf16x8*)(pa0 + k0);
        bf16x8 a1 = *(const bf16x8*)(pa1 + k0);
        bf16x8 b0 = *(const bf16x8*)(pb0 + k0);
        bf16x8 b1 = *(const bf16x8*)(pb1 + k0);
        acc00 = MFMA16(a0, b0, acc00);
        acc01 = MFMA16(a0, b1, acc01);
        acc10 = MFMA16(a1, b0, acc10);
        acc11 = MFMA16(a1, b1, acc11);
    }
#pragma unroll
    for (int r = 0; r < 4; r++) {
        int row0 = quad * 4 + r;
        int col0 = nw * 32 + l16;
        Sc[row0 * 132 + col0]            = acc00[r];
        Sc[row0 * 132 + col0 + 16]       = acc01[r];
        Sc[(row0 + 16) * 132 + col0]      = acc10[r];
        Sc[(row0 + 16) * 132 + col0 + 16] = acc11[r];
    }
    __syncthreads();
    for (int r = 0; r < 8; r++) {
        int row = wave * 8 + r;
        float v0 = Sc[row * 132 + lane];
        float v1 = Sc[row * 132 + 64 + lane];
        float mx = fmaxf(v0, v1);
#pragma unroll
        for (int off = 32; off > 0; off >>= 1) mx = fmaxf(mx, __shfl_xor(mx, off));
        float e0 = __expf(v0 - mx), e1 = __expf(v1 - mx);
        float s = e0 + e1;
#pragma unroll
        for (int off = 32; off > 0; off >>= 1) s += __shfl_xor(s, off);
        float inv = 1.0f / s;
        float p0 = e0 * inv, p1 = e1 * inv;
        long o = ((long)b * T_ + row) * S_;
        probs[o + lane] = p0;
        probs[o + 64 + lane] = p1;
        PB[o + lane] = f2bf(p0);
        PB[o + 64 + lane] = f2bf(p1);
    }
}

// ---------------------------------------------------------------------------
// ctx: C[b] = P[b](32x128) @ encB[b](128x1024) -> CTX bf16. grid(B, 4).
// ---------------------------------------------------------------------------
__global__ __launch_bounds__(256) void ctx_kernel(
    const unsigned short* __restrict__ encB, // [B][S][H]
    const unsigned short* __restrict__ PB,   // [B][T][S]
    unsigned short* __restrict__ ctxo)       // [B*T][H] bf16
{
    __shared__ unsigned short Es[S_ * 256];  // 64 KB

    const int tid = threadIdx.x;
    const int lane = tid & 63, wave = tid >> 6;
    const int quad = lane >> 4, l16 = lane & 15;
    const int b = blockIdx.x;
    const int h0 = blockIdx.y * 256;

    for (int i = tid; i < S_ * 32; i += 256) {
        int s = i >> 5, hc = (i & 31) * 8;
        *(uint4*)(Es + s * 256 + hc) =
            *(const uint4*)(encB + ((long)b * S_ + s) * H_ + h0 + hc);
    }
    bf16x8 a[2][4];
#pragma unroll
    for (int i = 0; i < 2; i++)
#pragma unroll
        for (int ks = 0; ks < 4; ks++)
            a[i][ks] = *(const bf16x8*)(PB + ((long)b * T_ + i * 16 + l16) * S_ +
                                        ks * 32 + quad * 8);
    __syncthreads();

    f32x4 acc[2][4];
    const f32x4 z = {0.f, 0.f, 0.f, 0.f};
#pragma unroll
    for (int i = 0; i < 2; i++)
#pragma unroll
        for (int j = 0; j < 4; j++) acc[i][j] = z;

    const int cw = wave * 64;
#pragma unroll
    for (int ks = 0; ks < 4; ks++) {
        const int kb = ks * 32 + quad * 8;
#pragma unroll
        for (int j = 0; j < 4; j++) {
            const int col = cw + j * 16 + l16;
            bf16x8 bb;
#pragma unroll
            for (int e = 0; e < 8; e++) bb[e] = (short)Es[(kb + e) * 256 + col];
            acc[0][j] = MFMA16(a[0][ks], bb, acc[0][j]);
            acc[1][j] = MFMA16(a[1][ks], bb, acc[1][j]);
        }
    }
#pragma unroll
    for (int i = 0; i < 2; i++)
#pragma unroll
        for (int j = 0; j < 4; j++)
#pragma unroll
            for (int r = 0; r < 4; r++) {
                int row = i * 16 + quad * 4 + r;
                int col = h0 + cw + j * 16 + l16;
                ctxo[((long)b * T_ + row) * H_ + col] = f2bf(acc[i][j][r]);
            }
}

// ---------------------------------------------------------------------------
// fc: out = [ctx | h](8192x2048) @ WfcR^T (256x2048) + bfc. grid(2,128).
// ---------------------------------------------------------------------------
__global__ __launch_bounds__(256) void fc_kernel(
    const unsigned short* __restrict__ ctxo, // [B*T][H]
    const unsigned short* __restrict__ hall, // [B*T][H]
    const unsigned short* __restrict__ WfcR,
    const float* __restrict__ bfc,
    float* __restrict__ out)
{
    __shared__ __align__(16) unsigned short As[64 * 40];
    __shared__ __align__(16) unsigned short Bs[128 * 40];

    const int tid = threadIdx.x;
    const int lane = tid & 63, wave = tid >> 6;
    const int wm = wave >> 1, wn = wave & 1;
    const int quad = lane >> 4, l16 = lane & 15;
    const int n0 = blockIdx.x * 128, m0 = blockIdx.y * 64;

    const int arow = tid >> 2, akc = (tid & 3) * 8;
    const int brow = tid >> 1, bkc = (tid & 1) * 16;

    f32x4 acc[2][4];
    const f32x4 z = {0.f, 0.f, 0.f, 0.f};
#pragma unroll
    for (int i = 0; i < 2; i++)
#pragma unroll
        for (int j = 0; j < 4; j++) acc[i][j] = z;

    for (int k0 = 0; k0 < K2; k0 += 32) {
        const unsigned short* asrc = (k0 < H_)
            ? ctxo + (long)(m0 + arow) * H_ + k0 + akc
            : hall + (long)(m0 + arow) * H_ + (k0 - H_) + akc;
        *(uint4*)(As + arow * 40 + akc) = *(const uint4*)asrc;
        const unsigned short* src = WfcR + (long)(n0 + brow) * K2 + k0 + bkc;
        *(uint4*)(Bs + brow * 40 + bkc)     = *(const uint4*)src;
        *(uint4*)(Bs + brow * 40 + bkc + 8) = *(const uint4*)(src + 8);
        __syncthreads();
        bf16x8 a0 = *(const bf16x8*)(As + (wm * 32 + l16) * 40 + quad * 8);
        bf16x8 a1 = *(const bf16x8*)(As + (wm * 32 + 16 + l16) * 40 + quad * 8);
#pragma unroll
        for (int j = 0; j < 4; j++) {
            bf16x8 bb = *(const bf16x8*)(Bs + (wn * 64 + j * 16 + l16) * 40 + quad * 8);
            acc[0][j] = MFMA16(a0, bb, acc[0][j]);
            acc[1][j] = MFMA16(a1, bb, acc[1][j]);
        }
        __syncthreads();
    }
#pragma unroll
    for (int i = 0; i < 2; i++)
#pragma unroll
        for (int j = 0; j < 4; j++)
#pragma unroll
            for (int r = 0; r < 4; r++) {
                int row = m0 + wm * 32 + i * 16 + quad * 4 + r;
                int col = n0 + wn * 64 + j * 16 + l16;
                out[(long)row * O_ + col] = acc[i][j][r] + bfc[col];
            }
}

// ---------------------------------------------------------------------------
extern "C" void kernel_launch(void* const* d_in, const int* in_sizes, int n_in,
                              void* d_out, int out_size, void* d_ws, size_t ws_size,
                              hipStream_t stream) {
    const float* x   = (const float*)d_in[0];
    const float* enc = (const float*)d_in[1];
    const float* Wih = (const float*)d_in[2];
    const float* Whh = (const float*)d_in[3];
    const float* bih = (const float*)d_in[4];
    const float* bhh = (const float*)d_in[5];
    const float* Wfc = (const float*)d_in[6];
    const float* bfc = (const float*)d_in[7];
    float* out = (float*)d_out;

    char* ws = (char*)d_ws;
    // workspace layout (bytes); total ~119.6 MB
    unsigned short* WIHR = (unsigned short*)(ws + 0);           //  2,097,152
    unsigned short* WHHR = (unsigned short*)(ws + 2097152);     //  8,388,608
    unsigned short* WFCR = (unsigned short*)(ws + 10485760);    //  1,048,576
    float*          BIAS = (float*)         (ws + 11534336);    //     16,384
    unsigned short* XS   = (unsigned short*)(ws + 11550720);    //  4,194,304
    unsigned short* H0   = (unsigned short*)(ws + 15745024);    //    524,288
    unsigned short* H1   = (unsigned short*)(ws + 16269312);    //    524,288
    unsigned short* HALL = (unsigned short*)(ws + 16793600);    // 16,777,216
    unsigned short* ENCB = (unsigned short*)(ws + 33570816);    // 67,108,864
    unsigned short* PB   = (unsigned short*)(ws + 100679680);   //  2,097,152
    unsigned short* CTX  = (unsigned short*)(ws + 102776832);   // 16,777,216
    unsigned int*   BAR  = (unsigned int*)  (ws + 119554048);   //      1,024

    hipMemsetAsync(BAR, 0, 1024, stream);

    prep_kernel<<<4096, 256, 0, stream>>>(x, enc, Wih, Whh, bih, bhh, Wfc,
                                          WIHR, WHHR, WFCR, BIAS, XS, ENCB, H0);

    rec_kernel<<<256, 512, 0, stream>>>(XS, WIHR, WHHR, BIAS, H0, H1, HALL, BAR);

    scores_kernel<<<B_, 256, 0, stream>>>(HALL, ENCB,
                                          out + (long)B_ * T_ * O_, PB);
    ctx_kernel<<<dim3(B_, 4), 256, 0, stream>>>(ENCB, PB, CTX);
    fc_kernel<<<dim3(2, 128), 256, 0, stream>>>(CTX, HALL, WFCR, bfc, out);
}